// Round 3
// baseline (143.156 us; speedup 1.0000x reference)
//
#include <hip/hip_runtime.h>
#include <hip/hip_bf16.h>

#define NB 4
#define NQ 1024
#define NKS 1024
#define ND 256
#define NH 8
#define NHD 32
#define NOUT 256
#define SPLIT 2

typedef __attribute__((ext_vector_type(8))) short v8s;
typedef __attribute__((ext_vector_type(4))) short v4s;
typedef __attribute__((ext_vector_type(4))) float f32x4;

// ---------------- prep: f32 activations -> bf16 ----------------
__global__ __launch_bounds__(256) void prep_data(
    const float* __restrict__ qd, const float* __restrict__ md,
    __hip_bfloat16* __restrict__ Abf)
{
  const int gid = blockIdx.x * 256 + threadIdx.x;     // 0..262143
  const float* src = (gid < 131072) ? qd : md;
  const size_t off = (size_t)(gid & 131071) * 8;
  const float4 a = ((const float4*)(src + off))[0];
  const float4 c = ((const float4*)(src + off))[1];
  __hip_bfloat16 t8[8];
  t8[0]=__float2bfloat16(a.x); t8[1]=__float2bfloat16(a.y);
  t8[2]=__float2bfloat16(a.z); t8[3]=__float2bfloat16(a.w);
  t8[4]=__float2bfloat16(c.x); t8[5]=__float2bfloat16(c.y);
  t8[6]=__float2bfloat16(c.z); t8[7]=__float2bfloat16(c.w);
  *(v8s*)(Abf + (size_t)gid * 8) = *(v8s*)t8;
}

// ---------------- prep: weight transpose -> bf16 [out][d] ----------------
// m: 0=query(scaled), 1=key, 2=value, 3=gating
__global__ __launch_bounds__(256) void prep_w(
    const float* __restrict__ qw, const float* __restrict__ kw,
    const float* __restrict__ vw, const float* __restrict__ gw,
    __hip_bfloat16* __restrict__ Wt)
{
  __shared__ float tile[64][65];
  const int m = blockIdx.y;
  const float* src = (m == 0) ? qw : (m == 1) ? kw : (m == 2) ? vw : gw;
  const float scale = (m == 0) ? 0.1767766952966369f : 1.0f;
  const int d0 = (blockIdx.x >> 2) * 64, o0 = (blockIdx.x & 3) * 64;
  #pragma unroll
  for (int i = 0; i < 16; ++i) {
    const int idx = threadIdx.x + i * 256;
    tile[idx >> 6][idx & 63] = src[(size_t)(d0 + (idx >> 6)) * 256 + o0 + (idx & 63)];
  }
  __syncthreads();
  __hip_bfloat16* dst = Wt + (size_t)m * 65536;
  #pragma unroll
  for (int i = 0; i < 16; ++i) {
    const int idx = threadIdx.x + i * 256;
    const int orow = idx >> 6, dc = idx & 63;
    dst[(size_t)(o0 + orow) * 256 + d0 + dc] = __float2bfloat16(tile[dc][orow] * scale);
  }
}

// ---------------- Kernel 1: MFMA projections ----------------
// grid 512 x 64: src = bx>>8 (0: qdata -> Qw,G ; 1: mdata -> Kw,Vt)
__global__ __launch_bounds__(64) void proj_kernel(
    const __hip_bfloat16* __restrict__ Abf, const __hip_bfloat16* __restrict__ Wt,
    const float* __restrict__ gating_b,
    __hip_bfloat16* __restrict__ Qw, __hip_bfloat16* __restrict__ Kw,
    __hip_bfloat16* __restrict__ Vt, float* __restrict__ G)
{
  const int lane = threadIdx.x;
  const int c = lane & 15, g = lane >> 4;
  const int src = blockIdx.x >> 8;
  const int r0 = (blockIdx.x & 255) * 16;     // flat row base within source
  const int b = r0 >> 10, pos0 = r0 & 1023;
  const f32x4 z = {0.f, 0.f, 0.f, 0.f};

  const __hip_bfloat16* A = Abf + ((size_t)src * 4096 + r0) * 256;
  v8s af[8];
  #pragma unroll
  for (int ks = 0; ks < 8; ++ks)
    af[ks] = *(const v8s*)(A + c * 256 + ks * 32 + g * 8);

  // ---- matrix 1 (normal orientation): Q (src0) or K (src1) ----
  {
    const __hip_bfloat16* W1 = Wt + (size_t)src * 65536;   // 0=query,1=key
    __hip_bfloat16* dst = src ? Kw : Qw;
    #pragma unroll
    for (int ctg = 0; ctg < 4; ++ctg) {
      f32x4 ac[4] = {z, z, z, z};
      #pragma unroll
      for (int ks = 0; ks < 8; ++ks) {
        #pragma unroll
        for (int j = 0; j < 4; ++j) {
          v8s wf = *(const v8s*)(W1 + (size_t)((ctg * 4 + j) * 16 + c) * 256 + ks * 32 + g * 8);
          ac[j] = __builtin_amdgcn_mfma_f32_16x16x32_bf16(af[ks], wf, ac[j], 0, 0, 0);
        }
      }
      #pragma unroll
      for (int j = 0; j < 4; ++j) {
        const int o = (ctg * 4 + j) * 16 + c, h = o >> 5, hd = o & 31;
        #pragma unroll
        for (int r = 0; r < 4; ++r)
          dst[((size_t)(b * NH + h) * 1024 + pos0 + 4 * g + r) * 32 + hd] =
              __float2bfloat16(ac[j][r]);
      }
    }
  }

  // ---- matrix 2: gating (src0, normal) or value (src1, swapped) ----
  if (src == 0) {
    const __hip_bfloat16* W2 = Wt + (size_t)3 * 65536;     // gating
    #pragma unroll
    for (int ctg = 0; ctg < 4; ++ctg) {
      f32x4 ac[4] = {z, z, z, z};
      #pragma unroll
      for (int ks = 0; ks < 8; ++ks) {
        #pragma unroll
        for (int j = 0; j < 4; ++j) {
          v8s wf = *(const v8s*)(W2 + (size_t)((ctg * 4 + j) * 16 + c) * 256 + ks * 32 + g * 8);
          ac[j] = __builtin_amdgcn_mfma_f32_16x16x32_bf16(af[ks], wf, ac[j], 0, 0, 0);
        }
      }
      #pragma unroll
      for (int j = 0; j < 4; ++j) {
        const int o = (ctg * 4 + j) * 16 + c;
        const float gb = gating_b[o];
        #pragma unroll
        for (int r = 0; r < 4; ++r)
          G[(size_t)(r0 + 4 * g + r) * 256 + o] = ac[j][r] + gb;
      }
    }
  } else {
    const __hip_bfloat16* W2 = Wt + (size_t)2 * 65536;     // value, swapped operands
    #pragma unroll
    for (int ctg = 0; ctg < 4; ++ctg) {
      f32x4 ac[4] = {z, z, z, z};
      #pragma unroll
      for (int ks = 0; ks < 8; ++ks) {
        #pragma unroll
        for (int j = 0; j < 4; ++j) {
          v8s wf = *(const v8s*)(W2 + (size_t)((ctg * 4 + j) * 16 + c) * 256 + ks * 32 + g * 8);
          ac[j] = __builtin_amdgcn_mfma_f32_16x16x32_bf16(wf, af[ks], ac[j], 0, 0, 0);
        }
      }
      // lane(c,g) reg r holds V[pos = pos0+c][o = ct*16+4g+r] -> coalesced Vt write
      #pragma unroll
      for (int j = 0; j < 4; ++j) {
        #pragma unroll
        for (int r = 0; r < 4; ++r) {
          const int o2 = (ctg * 4 + j) * 16 + 4 * g + r;
          Vt[((size_t)(b * NH + (o2 >> 5)) * 32 + (o2 & 31)) * 1024 + pos0 + c] =
              __float2bfloat16(ac[j][r]);
        }
      }
    }
  }
}

// ---------------- Kernel 2: split-K barrier-free flash attention ----------------
// grid = SPLIT * B*H*(Q/16) = 4096 waves; each covers K-range of 512.
__global__ __launch_bounds__(64) void attn_kernel(
    const __hip_bfloat16* __restrict__ Qw, const __hip_bfloat16* __restrict__ Kw,
    const __hip_bfloat16* __restrict__ Vt,
    const float* __restrict__ bias, const float* __restrict__ nbb,
    float* __restrict__ out_logits, float* __restrict__ part)
{
  __shared__ __align__(16) __hip_bfloat16 sP[16][72];

  const int lane = threadIdx.x;
  const int c = lane & 15, g = lane >> 4;
  const int rem = blockIdx.x & 2047;
  const int sp  = blockIdx.x >> 11;
  const int qt = rem & 63;
  const int h  = (rem >> 6) & 7;
  const int b  = rem >> 9;
  const int q0 = qt * 16;
  const int kbase = sp * (NKS / SPLIT);
  const size_t bh = (size_t)(b * NH + h);

  const __hip_bfloat16* Kbase = Kw + bh * NKS * NHD;
  const __hip_bfloat16* Vbase = Vt + bh * NHD * NKS;
  const float* biasb = bias + (size_t)b * NKS;
  const float* nbbb  = nbb + ((size_t)h * NQ + q0) * NKS;

  const v8s qfrag = *(const v8s*)(Qw + (bh * NQ + q0 + c) * NHD + g * 8);

  const f32x4 zacc = {0.f, 0.f, 0.f, 0.f};
  f32x4 O0 = zacc, O1 = zacc;
  const float NEG_INF = -__builtin_inff();
  float m[4], lsum[4];
  #pragma unroll
  for (int r = 0; r < 4; ++r) { m[r] = NEG_INF; lsum[r] = 0.f; }

  auto loadKV = [&](int k0, v8s* kf, v8s* vf) {
    kf[0] = *(const v8s*)(Kbase + (k0 +      c) * NHD + g * 8);
    kf[1] = *(const v8s*)(Kbase + (k0 + 16 + c) * NHD + g * 8);
    kf[2] = *(const v8s*)(Kbase + (k0 + 32 + c) * NHD + g * 8);
    kf[3] = *(const v8s*)(Kbase + (k0 + 48 + c) * NHD + g * 8);
    vf[0] = *(const v8s*)(Vbase + (     c) * NKS + k0 +      g * 8);
    vf[1] = *(const v8s*)(Vbase + (16 + c) * NKS + k0 +      g * 8);
    vf[2] = *(const v8s*)(Vbase + (     c) * NKS + k0 + 32 + g * 8);
    vf[3] = *(const v8s*)(Vbase + (16 + c) * NKS + k0 + 32 + g * 8);
  };
  auto loadBias = [&](int k0, float* nb, float* bv) {
    #pragma unroll
    for (int t = 0; t < 4; ++t) {
      bv[t] = biasb[k0 + t * 16 + c];
      #pragma unroll
      for (int r = 0; r < 4; ++r)
        nb[t * 4 + r] = nbbb[(g * 4 + r) * NKS + k0 + t * 16 + c];
    }
  };

  auto compute = [&](int k0, const v8s* kf, const v8s* vf,
                     const float* nb, const float* bv) {
    f32x4 S[4];
    #pragma unroll
    for (int t = 0; t < 4; ++t)
      S[t] = __builtin_amdgcn_mfma_f32_16x16x32_bf16(qfrag, kf[t], zacc, 0, 0, 0);

    float l[4][4];
    #pragma unroll
    for (int r = 0; r < 4; ++r) {
      const int qrow = q0 + g * 4 + r;
      float* lp = out_logits + (bh * NQ + qrow) * (size_t)NKS + k0 + c;
      #pragma unroll
      for (int t = 0; t < 4; ++t) {
        __builtin_nontemporal_store(S[t][r], lp + t * 16);
        l[r][t] = S[t][r] + bv[t] + nb[t * 4 + r];
      }
    }

    #pragma unroll
    for (int r = 0; r < 4; ++r) {
      float x = fmaxf(fmaxf(l[r][0], l[r][1]), fmaxf(l[r][2], l[r][3]));
      x = fmaxf(x, __shfl_xor(x, 1));
      x = fmaxf(x, __shfl_xor(x, 2));
      x = fmaxf(x, __shfl_xor(x, 4));
      x = fmaxf(x, __shfl_xor(x, 8));
      const float mn = fmaxf(m[r], x);
      const float sc = __expf(m[r] - mn);
      float p[4];
      float rs = 0.f;
      #pragma unroll
      for (int t = 0; t < 4; ++t) { p[t] = __expf(l[r][t] - mn); rs += p[t]; }
      rs += __shfl_xor(rs, 1);
      rs += __shfl_xor(rs, 2);
      rs += __shfl_xor(rs, 4);
      rs += __shfl_xor(rs, 8);
      lsum[r] = lsum[r] * sc + rs;
      m[r] = mn;
      O0[r] *= sc; O1[r] *= sc;
      #pragma unroll
      for (int t = 0; t < 4; ++t)
        sP[g * 4 + r][t * 16 + c] = __float2bfloat16(p[t]);
    }

    const v8s pa0 = *(const v8s*)&sP[c][g * 8];
    const v8s pa1 = *(const v8s*)&sP[c][32 + g * 8];
    O0 = __builtin_amdgcn_mfma_f32_16x16x32_bf16(pa0, vf[0], O0, 0, 0, 0);
    O0 = __builtin_amdgcn_mfma_f32_16x16x32_bf16(pa1, vf[2], O0, 0, 0, 0);
    O1 = __builtin_amdgcn_mfma_f32_16x16x32_bf16(pa0, vf[1], O1, 0, 0, 0);
    O1 = __builtin_amdgcn_mfma_f32_16x16x32_bf16(pa1, vf[3], O1, 0, 0, 0);
  };

  v8s kfA[4], vfA[4], kfB[4], vfB[4];
  float nbA[16], bvA[4], nbB[16], bvB[4];

  loadKV(kbase, kfA, vfA);
  loadBias(kbase, nbA, bvA);
  #pragma unroll 1
  for (int kt = 0; kt < 8; kt += 2) {
    loadKV(kbase + (kt + 1) * 64, kfB, vfB);
    loadBias(kbase + (kt + 1) * 64, nbB, bvB);
    compute(kbase + kt * 64, kfA, vfA, nbA, bvA);
    if (kt + 2 < 8) {
      loadKV(kbase + (kt + 2) * 64, kfA, vfA);
      loadBias(kbase + (kt + 2) * 64, nbA, bvA);
    }
    compute(kbase + (kt + 1) * 64, kfB, vfB, nbB, bvB);
  }

  // write partials: [rem][sp][16 rows][36]  (O[32], m, l)
  float* P = part + ((size_t)rem * SPLIT + sp) * (16 * 36);
  #pragma unroll
  for (int r = 0; r < 4; ++r) {
    const int row = 4 * g + r;
    P[row * 36 + c]      = O0[r];
    P[row * 36 + 16 + c] = O1[r];
    if (c == 0) { P[row * 36 + 32] = m[r]; P[row * 36 + 33] = lsum[r]; }
  }
}

// ---------------- Kernel 2b: merge split-K partials ----------------
__global__ __launch_bounds__(64) void merge_kernel(
    const float* __restrict__ part, float* __restrict__ WA)
{
  const int rem = blockIdx.x;
  const int qt = rem & 63, h = (rem >> 6) & 7, b = rem >> 9;
  const int lane = threadIdx.x;
  const int row = lane >> 2, q = lane & 3;

  const float* P0 = part + ((size_t)rem * SPLIT + 0) * (16 * 36);
  const float* P1 = part + ((size_t)rem * SPLIT + 1) * (16 * 36);
  const float m0 = P0[row * 36 + 32], l0 = P0[row * 36 + 33];
  const float m1 = P1[row * 36 + 32], l1 = P1[row * 36 + 33];
  const float mm = fmaxf(m0, m1);
  const float w0 = __expf(m0 - mm), w1 = __expf(m1 - mm);
  const float inv = 1.0f / (l0 * w0 + l1 * w1);

  const f32x4 a0 = *(const f32x4*)&P0[row * 36 + q * 8];
  const f32x4 a1 = *(const f32x4*)&P0[row * 36 + q * 8 + 4];
  const f32x4 b0 = *(const f32x4*)&P1[row * 36 + q * 8];
  const f32x4 b1 = *(const f32x4*)&P1[row * 36 + q * 8 + 4];
  f32x4 o0 = (a0 * w0 + b0 * w1) * inv;
  f32x4 o1 = (a1 * w0 + b1 * w1) * inv;

  float* wp = WA + ((size_t)b * NQ + qt * 16 + row) * 256 + h * NHD + q * 8;
  *(f32x4*)wp = o0;
  *(f32x4*)(wp + 4) = o1;
}

// ---------------- Kernel 3: sigmoid gate + output projection ----------------
__global__ __launch_bounds__(256) void outproj_kernel(
    const float* __restrict__ WA, const float* __restrict__ G,
    const float* __restrict__ output_w, const float* __restrict__ output_b,
    float* __restrict__ out)
{
  __shared__ float rows[16][256];
  const int t = threadIdx.x;
  const int r0 = blockIdx.x * 16;
  for (int i = t; i < 4096; i += 256) {
    const int r = i >> 8, dcol = i & 255;
    const size_t idx = (size_t)(r0 + r) * 256 + dcol;
    const float gl = G[idx];
    rows[r][dcol] = WA[idx] * (1.f / (1.f + __expf(-gl)));
  }
  __syncthreads();

  float acc[16];
  const float ob = output_b[t];
  #pragma unroll
  for (int r = 0; r < 16; ++r) acc[r] = ob;

  for (int d0 = 0; d0 < 256; d0 += 8) {
    float w[8];
    #pragma unroll
    for (int j = 0; j < 8; ++j) w[j] = output_w[(d0 + j) * 256 + t];
    #pragma unroll
    for (int r = 0; r < 16; ++r) {
      float4 x0 = *(const float4*)&rows[r][d0];
      float4 x1 = *(const float4*)&rows[r][d0 + 4];
      acc[r] += x0.x*w[0] + x0.y*w[1] + x0.z*w[2] + x0.w*w[3]
              + x1.x*w[4] + x1.y*w[5] + x1.z*w[6] + x1.w*w[7];
    }
  }
  #pragma unroll
  for (int r = 0; r < 16; ++r)
    out[(size_t)(r0 + r) * 256 + t] = acc[r];
}

extern "C" void kernel_launch(void* const* d_in, const int* in_sizes, int n_in,
                              void* d_out, int out_size, void* d_ws, size_t ws_size,
                              hipStream_t stream) {
  const float* q_data   = (const float*)d_in[0];
  const float* m_data   = (const float*)d_in[1];
  const float* bias     = (const float*)d_in[2];
  const float* nbb      = (const float*)d_in[3];
  const float* query_w  = (const float*)d_in[4];
  const float* key_w    = (const float*)d_in[5];
  const float* value_w  = (const float*)d_in[6];
  const float* gating_w = (const float*)d_in[7];
  const float* gating_b = (const float*)d_in[8];
  const float* output_w = (const float*)d_in[9];
  const float* output_b = (const float*)d_in[10];

  float* out        = (float*)d_out;
  float* out_logits = out + (size_t)NB * NQ * NOUT;

  char* ws = (char*)d_ws;
  const size_t MB = 1u << 20;
  __hip_bfloat16* Qw  = (__hip_bfloat16*)(ws);              // 2MB
  __hip_bfloat16* Kw  = (__hip_bfloat16*)(ws + 2 * MB);     // 2MB
  __hip_bfloat16* Vt  = (__hip_bfloat16*)(ws + 4 * MB);     // 2MB
  float*          G   = (float*)(ws + 6 * MB);              // 4MB
  float*          WA  = (float*)(ws + 10 * MB);             // 4MB
  __hip_bfloat16* Abf = (__hip_bfloat16*)(ws + 14 * MB);    // 4MB
  __hip_bfloat16* Wt  = (__hip_bfloat16*)(ws + 18 * MB);    // 640KB
  float*          part= (float*)(ws + 19 * MB);             // 9.4MB

  prep_data<<<1024, 256, 0, stream>>>(q_data, m_data, Abf);
  prep_w<<<dim3(16, 4), 256, 0, stream>>>(query_w, key_w, value_w, gating_w, Wt);
  proj_kernel<<<512, 64, 0, stream>>>(Abf, Wt, gating_b, Qw, Kw, Vt, G);
  attn_kernel<<<2048 * SPLIT, 64, 0, stream>>>(Qw, Kw, Vt, bias, nbb, out_logits, part);
  merge_kernel<<<2048, 64, 0, stream>>>(part, WA);
  outproj_kernel<<<256, 256, 0, stream>>>(WA, G, output_w, output_b, out);
}

// Round 4
// 117.281 us; speedup vs baseline: 1.2206x; 1.2206x over previous
//
#include <hip/hip_runtime.h>
#include <hip/hip_bf16.h>

#define NB 4
#define NQ 1024
#define NKS 1024
#define ND 256
#define NH 8
#define NHD 32
#define NOUT 256
#define SPLIT 2

typedef __attribute__((ext_vector_type(8))) short v8s;
typedef __attribute__((ext_vector_type(4))) short v4s;
typedef __attribute__((ext_vector_type(4))) float f32x4;

// ---------------- prep: f32 activations -> bf16 ----------------
__global__ __launch_bounds__(256) void prep_data(
    const float* __restrict__ qd, const float* __restrict__ md,
    __hip_bfloat16* __restrict__ Abf)
{
  const int gid = blockIdx.x * 256 + threadIdx.x;     // 0..262143
  const float* src = (gid < 131072) ? qd : md;
  const size_t off = (size_t)(gid & 131071) * 8;
  const float4 a = ((const float4*)(src + off))[0];
  const float4 c = ((const float4*)(src + off))[1];
  __hip_bfloat16 t8[8];
  t8[0]=__float2bfloat16(a.x); t8[1]=__float2bfloat16(a.y);
  t8[2]=__float2bfloat16(a.z); t8[3]=__float2bfloat16(a.w);
  t8[4]=__float2bfloat16(c.x); t8[5]=__float2bfloat16(c.y);
  t8[6]=__float2bfloat16(c.z); t8[7]=__float2bfloat16(c.w);
  *(v8s*)(Abf + (size_t)gid * 8) = *(v8s*)t8;
}

// ---------------- prep: weight transpose -> bf16 [out][d] ----------------
// m: 0=query(scaled), 1=key, 2=value, 3=gating
__global__ __launch_bounds__(256) void prep_w(
    const float* __restrict__ qw, const float* __restrict__ kw,
    const float* __restrict__ vw, const float* __restrict__ gw,
    __hip_bfloat16* __restrict__ Wt)
{
  __shared__ float tile[64][65];
  const int m = blockIdx.y;
  const float* src = (m == 0) ? qw : (m == 1) ? kw : (m == 2) ? vw : gw;
  const float scale = (m == 0) ? 0.1767766952966369f : 1.0f;
  const int d0 = (blockIdx.x >> 2) * 64, o0 = (blockIdx.x & 3) * 64;
  #pragma unroll
  for (int i = 0; i < 16; ++i) {
    const int idx = threadIdx.x + i * 256;
    tile[idx >> 6][idx & 63] = src[(size_t)(d0 + (idx >> 6)) * 256 + o0 + (idx & 63)];
  }
  __syncthreads();
  __hip_bfloat16* dst = Wt + (size_t)m * 65536;
  #pragma unroll
  for (int i = 0; i < 16; ++i) {
    const int idx = threadIdx.x + i * 256;
    const int orow = idx >> 6, dc = idx & 63;
    dst[(size_t)(o0 + orow) * 256 + d0 + dc] = __float2bfloat16(tile[dc][orow] * scale);
  }
}

// ---------------- Kernel 1: MFMA projections, 4 waves/block ----------------
// 4096 wave-tasks: task = ((src*256 + r0g)*2 + mat)*4 + ctg
__global__ __launch_bounds__(256) void proj_kernel(
    const __hip_bfloat16* __restrict__ Abf, const __hip_bfloat16* __restrict__ Wt,
    const float* __restrict__ gating_b,
    __hip_bfloat16* __restrict__ Qw, __hip_bfloat16* __restrict__ Kw,
    __hip_bfloat16* __restrict__ Vt, float* __restrict__ G)
{
  const int wv = threadIdx.x >> 6, lane = threadIdx.x & 63;
  const int c = lane & 15, g = lane >> 4;
  const int task = blockIdx.x * 4 + wv;
  const int ctg = task & 3;
  const int mat = (task >> 2) & 1;
  const int r0g = (task >> 3) & 255;
  const int src = task >> 11;
  const int r0 = r0g * 16;
  const int b = r0 >> 10, pos0 = r0 & 1023;
  const f32x4 z = {0.f, 0.f, 0.f, 0.f};

  const __hip_bfloat16* A = Abf + ((size_t)src * 4096 + r0) * 256;
  v8s af[8];
  #pragma unroll
  for (int ks = 0; ks < 8; ++ks)
    af[ks] = *(const v8s*)(A + c * 256 + ks * 32 + g * 8);

  const int widx = (src == 0) ? (mat ? 3 : 0) : (mat ? 2 : 1);
  const __hip_bfloat16* W = Wt + (size_t)widx * 65536;
  const bool swapped = (src == 1) && (mat == 1);   // value proj: direct Vt layout

  f32x4 ac[4] = {z, z, z, z};
  #pragma unroll
  for (int ks = 0; ks < 8; ++ks) {
    #pragma unroll
    for (int j = 0; j < 4; ++j) {
      v8s wf = *(const v8s*)(W + (size_t)((ctg * 4 + j) * 16 + c) * 256 + ks * 32 + g * 8);
      ac[j] = swapped
        ? __builtin_amdgcn_mfma_f32_16x16x32_bf16(wf, af[ks], ac[j], 0, 0, 0)
        : __builtin_amdgcn_mfma_f32_16x16x32_bf16(af[ks], wf, ac[j], 0, 0, 0);
    }
  }

  if (src == 0 && mat == 0) {          // Qw
    #pragma unroll
    for (int j = 0; j < 4; ++j) {
      const int o = (ctg * 4 + j) * 16 + c, h = o >> 5, hd = o & 31;
      #pragma unroll
      for (int r = 0; r < 4; ++r)
        Qw[((size_t)(b * NH + h) * 1024 + pos0 + 4 * g + r) * 32 + hd] =
            __float2bfloat16(ac[j][r]);
    }
  } else if (src == 0) {               // G (gating logits)
    #pragma unroll
    for (int j = 0; j < 4; ++j) {
      const int o = (ctg * 4 + j) * 16 + c;
      const float gb = gating_b[o];
      #pragma unroll
      for (int r = 0; r < 4; ++r)
        G[(size_t)(r0 + 4 * g + r) * 256 + o] = ac[j][r] + gb;
    }
  } else if (mat == 0) {               // Kw
    #pragma unroll
    for (int j = 0; j < 4; ++j) {
      const int o = (ctg * 4 + j) * 16 + c, h = o >> 5, hd = o & 31;
      #pragma unroll
      for (int r = 0; r < 4; ++r)
        Kw[((size_t)(b * NH + h) * 1024 + pos0 + 4 * g + r) * 32 + hd] =
            __float2bfloat16(ac[j][r]);
    }
  } else {                             // Vt (swapped): coalesced over pos
    #pragma unroll
    for (int j = 0; j < 4; ++j) {
      #pragma unroll
      for (int r = 0; r < 4; ++r) {
        const int o2 = (ctg * 4 + j) * 16 + 4 * g + r;
        Vt[((size_t)(b * NH + (o2 >> 5)) * 32 + (o2 & 31)) * 1024 + pos0 + c] =
            __float2bfloat16(ac[j][r]);
      }
    }
  }
}

// ---------------- Kernel 2: split-K flash attention, 4 waves/block ----------------
// grid = 1024 blocks x 256 thr; wave task: sp = bid&1, bh = (bid>>1)>>4,
// qt = ((bid>>1)&15)*4 + wv. Barrier-free; per-wave private sP slice.
__global__ __launch_bounds__(256) void attn_kernel(
    const __hip_bfloat16* __restrict__ Qw, const __hip_bfloat16* __restrict__ Kw,
    const __hip_bfloat16* __restrict__ Vt,
    const float* __restrict__ bias, const float* __restrict__ nbb,
    float* __restrict__ out_logits, float* __restrict__ part)
{
  __shared__ __align__(16) __hip_bfloat16 sP[4][16][72];

  const int wv = threadIdx.x >> 6, lane = threadIdx.x & 63;
  const int c = lane & 15, g = lane >> 4;
  const int sp  = blockIdx.x & 1;
  const int grp = blockIdx.x >> 1;
  const int bh  = grp >> 4;                 // 0..31
  const int qt  = (grp & 15) * 4 + wv;      // 0..63
  const int b = bh >> 3, h = bh & 7;
  const int rem = bh * 64 + qt;
  const int q0 = qt * 16;
  const int kbase = sp * (NKS / SPLIT);
  const size_t bhs = (size_t)bh;

  const __hip_bfloat16* Kbase = Kw + bhs * NKS * NHD;
  const __hip_bfloat16* Vbase = Vt + bhs * NHD * NKS;
  const float* biasb = bias + (size_t)b * NKS;
  const float* nbbb  = nbb + ((size_t)h * NQ + q0) * NKS;

  const v8s qfrag = *(const v8s*)(Qw + (bhs * NQ + q0 + c) * NHD + g * 8);

  const f32x4 zacc = {0.f, 0.f, 0.f, 0.f};
  f32x4 O0 = zacc, O1 = zacc;
  const float NEG_INF = -__builtin_inff();
  float m[4], lsum[4];
  #pragma unroll
  for (int r = 0; r < 4; ++r) { m[r] = NEG_INF; lsum[r] = 0.f; }

  auto loadKV = [&](int k0, v8s* kf, v8s* vf) {
    kf[0] = *(const v8s*)(Kbase + (k0 +      c) * NHD + g * 8);
    kf[1] = *(const v8s*)(Kbase + (k0 + 16 + c) * NHD + g * 8);
    kf[2] = *(const v8s*)(Kbase + (k0 + 32 + c) * NHD + g * 8);
    kf[3] = *(const v8s*)(Kbase + (k0 + 48 + c) * NHD + g * 8);
    vf[0] = *(const v8s*)(Vbase + (     c) * NKS + k0 +      g * 8);
    vf[1] = *(const v8s*)(Vbase + (16 + c) * NKS + k0 +      g * 8);
    vf[2] = *(const v8s*)(Vbase + (     c) * NKS + k0 + 32 + g * 8);
    vf[3] = *(const v8s*)(Vbase + (16 + c) * NKS + k0 + 32 + g * 8);
  };
  auto loadBias = [&](int k0, float* nb, float* bv) {
    #pragma unroll
    for (int t = 0; t < 4; ++t) {
      bv[t] = biasb[k0 + t * 16 + c];
      #pragma unroll
      for (int r = 0; r < 4; ++r)
        nb[t * 4 + r] = nbbb[(g * 4 + r) * NKS + k0 + t * 16 + c];
    }
  };

  auto compute = [&](int k0, const v8s* kf, const v8s* vf,
                     const float* nb, const float* bv) {
    f32x4 S[4];
    #pragma unroll
    for (int t = 0; t < 4; ++t)
      S[t] = __builtin_amdgcn_mfma_f32_16x16x32_bf16(qfrag, kf[t], zacc, 0, 0, 0);

    float l[4][4];
    #pragma unroll
    for (int r = 0; r < 4; ++r) {
      const int qrow = q0 + g * 4 + r;
      float* lp = out_logits + (bhs * NQ + qrow) * (size_t)NKS + k0 + c;
      #pragma unroll
      for (int t = 0; t < 4; ++t) {
        __builtin_nontemporal_store(S[t][r], lp + t * 16);
        l[r][t] = S[t][r] + bv[t] + nb[t * 4 + r];
      }
    }

    #pragma unroll
    for (int r = 0; r < 4; ++r) {
      float x = fmaxf(fmaxf(l[r][0], l[r][1]), fmaxf(l[r][2], l[r][3]));
      x = fmaxf(x, __shfl_xor(x, 1));
      x = fmaxf(x, __shfl_xor(x, 2));
      x = fmaxf(x, __shfl_xor(x, 4));
      x = fmaxf(x, __shfl_xor(x, 8));
      const float mn = fmaxf(m[r], x);
      const float sc = __expf(m[r] - mn);
      float p[4];
      float rs = 0.f;
      #pragma unroll
      for (int t = 0; t < 4; ++t) { p[t] = __expf(l[r][t] - mn); rs += p[t]; }
      rs += __shfl_xor(rs, 1);
      rs += __shfl_xor(rs, 2);
      rs += __shfl_xor(rs, 4);
      rs += __shfl_xor(rs, 8);
      lsum[r] = lsum[r] * sc + rs;
      m[r] = mn;
      O0[r] *= sc; O1[r] *= sc;
      #pragma unroll
      for (int t = 0; t < 4; ++t)
        sP[wv][g * 4 + r][t * 16 + c] = __float2bfloat16(p[t]);
    }

    const v8s pa0 = *(const v8s*)&sP[wv][c][g * 8];
    const v8s pa1 = *(const v8s*)&sP[wv][c][32 + g * 8];
    O0 = __builtin_amdgcn_mfma_f32_16x16x32_bf16(pa0, vf[0], O0, 0, 0, 0);
    O0 = __builtin_amdgcn_mfma_f32_16x16x32_bf16(pa1, vf[2], O0, 0, 0, 0);
    O1 = __builtin_amdgcn_mfma_f32_16x16x32_bf16(pa0, vf[1], O1, 0, 0, 0);
    O1 = __builtin_amdgcn_mfma_f32_16x16x32_bf16(pa1, vf[3], O1, 0, 0, 0);
  };

  v8s kfA[4], vfA[4], kfB[4], vfB[4];
  float nbA[16], bvA[4], nbB[16], bvB[4];

  loadKV(kbase, kfA, vfA);
  loadBias(kbase, nbA, bvA);
  #pragma unroll 1
  for (int kt = 0; kt < NKS / SPLIT / 64; kt += 2) {
    loadKV(kbase + (kt + 1) * 64, kfB, vfB);
    loadBias(kbase + (kt + 1) * 64, nbB, bvB);
    compute(kbase + kt * 64, kfA, vfA, nbA, bvA);
    if (kt + 2 < NKS / SPLIT / 64) {
      loadKV(kbase + (kt + 2) * 64, kfA, vfA);
      loadBias(kbase + (kt + 2) * 64, nbA, bvA);
    }
    compute(kbase + (kt + 1) * 64, kfB, vfB, nbB, bvB);
  }

  float* P = part + ((size_t)rem * SPLIT + sp) * (16 * 36);
  #pragma unroll
  for (int r = 0; r < 4; ++r) {
    const int row = 4 * g + r;
    P[row * 36 + c]      = O0[r];
    P[row * 36 + 16 + c] = O1[r];
    if (c == 0) { P[row * 36 + 32] = m[r]; P[row * 36 + 33] = lsum[r]; }
  }
}

// ---------------- Kernel 2b: merge split-K partials, 4 waves/block ----------------
__global__ __launch_bounds__(256) void merge_kernel(
    const float* __restrict__ part, float* __restrict__ WA)
{
  const int wv = threadIdx.x >> 6, lane = threadIdx.x & 63;
  const int rem = blockIdx.x * 4 + wv;
  const int qt = rem & 63, h = (rem >> 6) & 7, b = rem >> 9;
  const int row = lane >> 2, q = lane & 3;

  const float* P0 = part + ((size_t)rem * SPLIT + 0) * (16 * 36);
  const float* P1 = part + ((size_t)rem * SPLIT + 1) * (16 * 36);
  const float m0 = P0[row * 36 + 32], l0 = P0[row * 36 + 33];
  const float m1 = P1[row * 36 + 32], l1 = P1[row * 36 + 33];
  const float mm = fmaxf(m0, m1);
  const float w0 = __expf(m0 - mm), w1 = __expf(m1 - mm);
  const float inv = 1.0f / (l0 * w0 + l1 * w1);

  const f32x4 a0 = *(const f32x4*)&P0[row * 36 + q * 8];
  const f32x4 a1 = *(const f32x4*)&P0[row * 36 + q * 8 + 4];
  const f32x4 b0 = *(const f32x4*)&P1[row * 36 + q * 8];
  const f32x4 b1 = *(const f32x4*)&P1[row * 36 + q * 8 + 4];
  f32x4 o0 = (a0 * w0 + b0 * w1) * inv;
  f32x4 o1 = (a1 * w0 + b1 * w1) * inv;

  float* wp = WA + ((size_t)b * NQ + qt * 16 + row) * 256 + h * NHD + q * 8;
  *(f32x4*)wp = o0;
  *(f32x4*)(wp + 4) = o1;
}

// ---------------- Kernel 3: sigmoid gate + output projection ----------------
__global__ __launch_bounds__(256) void outproj_kernel(
    const float* __restrict__ WA, const float* __restrict__ G,
    const float* __restrict__ output_w, const float* __restrict__ output_b,
    float* __restrict__ out)
{
  __shared__ float rows[16][256];
  const int t = threadIdx.x;
  const int r0 = blockIdx.x * 16;
  for (int i = t; i < 4096; i += 256) {
    const int r = i >> 8, dcol = i & 255;
    const size_t idx = (size_t)(r0 + r) * 256 + dcol;
    const float gl = G[idx];
    rows[r][dcol] = WA[idx] * (1.f / (1.f + __expf(-gl)));
  }
  __syncthreads();

  float acc[16];
  const float ob = output_b[t];
  #pragma unroll
  for (int r = 0; r < 16; ++r) acc[r] = ob;

  for (int d0 = 0; d0 < 256; d0 += 8) {
    float w[8];
    #pragma unroll
    for (int j = 0; j < 8; ++j) w[j] = output_w[(d0 + j) * 256 + t];
    #pragma unroll
    for (int r = 0; r < 16; ++r) {
      float4 x0 = *(const float4*)&rows[r][d0];
      float4 x1 = *(const float4*)&rows[r][d0 + 4];
      acc[r] += x0.x*w[0] + x0.y*w[1] + x0.z*w[2] + x0.w*w[3]
              + x1.x*w[4] + x1.y*w[5] + x1.z*w[6] + x1.w*w[7];
    }
  }
  #pragma unroll
  for (int r = 0; r < 16; ++r)
    out[(size_t)(r0 + r) * 256 + t] = acc[r];
}

extern "C" void kernel_launch(void* const* d_in, const int* in_sizes, int n_in,
                              void* d_out, int out_size, void* d_ws, size_t ws_size,
                              hipStream_t stream) {
  const float* q_data   = (const float*)d_in[0];
  const float* m_data   = (const float*)d_in[1];
  const float* bias     = (const float*)d_in[2];
  const float* nbb      = (const float*)d_in[3];
  const float* query_w  = (const float*)d_in[4];
  const float* key_w    = (const float*)d_in[5];
  const float* value_w  = (const float*)d_in[6];
  const float* gating_w = (const float*)d_in[7];
  const float* gating_b = (const float*)d_in[8];
  const float* output_w = (const float*)d_in[9];
  const float* output_b = (const float*)d_in[10];

  float* out        = (float*)d_out;
  float* out_logits = out + (size_t)NB * NQ * NOUT;

  char* ws = (char*)d_ws;
  const size_t MB = 1u << 20;
  __hip_bfloat16* Qw  = (__hip_bfloat16*)(ws);              // 2MB
  __hip_bfloat16* Kw  = (__hip_bfloat16*)(ws + 2 * MB);     // 2MB
  __hip_bfloat16* Vt  = (__hip_bfloat16*)(ws + 4 * MB);     // 2MB
  float*          G   = (float*)(ws + 6 * MB);              // 4MB
  float*          WA  = (float*)(ws + 10 * MB);             // 4MB
  __hip_bfloat16* Abf = (__hip_bfloat16*)(ws + 14 * MB);    // 4MB
  __hip_bfloat16* Wt  = (__hip_bfloat16*)(ws + 18 * MB);    // 640KB
  float*          part= (float*)(ws + 19 * MB);             // 4.7MB

  prep_data<<<1024, 256, 0, stream>>>(q_data, m_data, Abf);
  prep_w<<<dim3(16, 4), 256, 0, stream>>>(query_w, key_w, value_w, gating_w, Wt);
  proj_kernel<<<1024, 256, 0, stream>>>(Abf, Wt, gating_b, Qw, Kw, Vt, G);
  attn_kernel<<<1024, 256, 0, stream>>>(Qw, Kw, Vt, bias, nbb, out_logits, part);
  merge_kernel<<<512, 256, 0, stream>>>(part, WA);
  outproj_kernel<<<256, 256, 0, stream>>>(WA, G, output_w, output_b, out);
}